// Round 1
// baseline (164.111 us; speedup 1.0000x reference)
//
#include <hip/hip_runtime.h>
#include <hip/hip_bf16.h>
#include <math.h>

#define NB 16
#define NC 16
#define NP 2048
#define NK 16
#define NE 64
#define NH 2
#define EPSV 1e-5f
#define NSLOPE 0.2f

// workspace byte offsets
#define WS_FLAGS   0                         // 2 ints: [0]=floats are bf16, [1]=mask is byte-width
#define WS_EW      256                       // edge_w as f32: H*E*C = 2048 floats
#define WS_SE      (WS_EW + 2048*4)          // s_e: 128 floats
#define WS_CBE     (WS_SE + 128*4)           // cbe: 128 floats
#define WS_WQ      (WS_CBE + 128*4)          // wq: 32 floats
#define WS_WSC     (WS_WQ + 32*4)            // wsc: 32 floats
#define WS_CNB     (WS_WSC + 32*4)           // cnb: 2 floats
#define WS_CSELF   (WS_CNB + 2*4)            // cself: 2 floats
#define WS_MASK8   10240                     // mask as u8: NB*NP = 32768 bytes
#define WS_QV      43008                     // q: NB*NH*NP floats = 262144 B
#define WS_SC      (WS_QV + 262144)          // self_score: NB*NH*NP floats
#define WS_EPROJ   (WS_SC + 262144)          // eproj [b][h][p][e] f32: 16 MiB

__device__ __forceinline__ float ldf(const void* p, int i, int isb) {
  return isb ? __bfloat162float(((const __hip_bfloat16*)p)[i]) : ((const float*)p)[i];
}

// ---------------- kernel 0: dtype detection + parameter folding (1 block) ----
__global__ void __launch_bounds__(256) k_pre(
    const void* feat, const void* mask,
    const void* node_w, const void* node_g, const void* node_b,
    const void* node_m, const void* node_v,
    const void* edge_w, const void* edge_bias, const void* edge_g,
    const void* edge_b2, const void* edge_m, const void* edge_v,
    const void* self_w, const void* self_b, const void* nb_w, const void* nb_b,
    char* ws)
{
  __shared__ int cnt_exp, cnt_msk;
  __shared__ int flags[2];
  __shared__ float w2[NH*NE], wn[NH*NE], contrib[NH*NE], contrib2[NH*NE];
  const int tid = threadIdx.x;
  if (tid == 0) { cnt_exp = 0; cnt_msk = 0; }
  __syncthreads();
  // float dtype: bf16 of N(0,1) has exponent field in a narrow band for ~100%
  // of samples; f32 halves are ~50% uniform -> ~57% in-band. Threshold 460/512.
  const unsigned short* u = (const unsigned short*)feat;
  for (int i = tid; i < 512; i += 256) {
    int ex = (u[i] >> 7) & 0xFF;
    if (ex >= 100 && ex <= 135) atomicAdd(&cnt_exp, 1);
  }
  // mask width: int32 0/1 values have all non-aligned bytes == 0
  const unsigned char* mb = (const unsigned char*)mask;
  for (int i = tid; i < 1024; i += 256) {
    if ((i & 3) && mb[i]) atomicAdd(&cnt_msk, 1);
  }
  __syncthreads();
  if (tid == 0) {
    flags[0] = (cnt_exp >= 460) ? 1 : 0;
    flags[1] = (cnt_msk > 0) ? 1 : 0;
    ((int*)ws)[0] = flags[0];
    ((int*)ws)[1] = flags[1];
  }
  __syncthreads();
  const int isb = flags[0];

  float* g_ew    = (float*)(ws + WS_EW);
  float* g_se    = (float*)(ws + WS_SE);
  float* g_cbe   = (float*)(ws + WS_CBE);
  float* g_wq    = (float*)(ws + WS_WQ);
  float* g_wsc   = (float*)(ws + WS_WSC);
  float* g_cnb   = (float*)(ws + WS_CNB);
  float* g_cself = (float*)(ws + WS_CSELF);

  for (int i = tid; i < NH*NE*NC; i += 256) g_ew[i] = ldf(edge_w, i, isb);

  if (tid < NH*NE) {
    const int he = tid;
    float se = ldf(edge_g, he, isb) * rsqrtf(ldf(edge_v, he, isb) + EPSV);
    float cb = se * (ldf(edge_bias, he, isb) - ldf(edge_m, he, isb)) + ldf(edge_b2, he, isb);
    float ns = ldf(node_g, he, isb) * rsqrtf(ldf(node_v, he, isb) + EPSV);
    w2[he] = ldf(nb_w, he, isb) * se;
    wn[he] = ldf(self_w, he, isb) * ns;
    g_se[he] = se;
    g_cbe[he] = cb;
    contrib[he]  = ldf(self_w, he, isb) * (ldf(node_b, he, isb) - ldf(node_m, he, isb) * ns);
    contrib2[he] = ldf(nb_w, he, isb) * cb;
  }
  __syncthreads();
  if (tid < NH*NC) {           // wq[h][c], wsc[h][c]
    const int h = tid >> 4, c = tid & 15;
    float sq = 0.f, sn = 0.f;
    for (int e = 0; e < NE; e++) {
      sq += w2[h*NE+e] * g_ew[(h*NE+e)*NC + c];
      sn += wn[h*NE+e] * ldf(node_w, (h*NE+e)*NC + c, isb);
    }
    g_wq[tid]  = sq;
    g_wsc[tid] = sn;
  }
  if (tid < NH) {
    float cs = 0.f, cn = 0.f;
    for (int e = 0; e < NE; e++) { cs += contrib[tid*NE+e]; cn += contrib2[tid*NE+e]; }
    g_cself[tid] = cs + ldf(self_b, tid, isb);
    g_cnb[tid]   = cn + ldf(nb_b, tid, isb);
  }
}

// ---------------- kernel 1: projection eproj[b][h][p][e], q, self_score ------
__global__ void __launch_bounds__(256) k_proj(const void* feat, const void* mask, char* ws)
{
  const int isb   = ((const int*)ws)[0];
  const int mbyte = ((const int*)ws)[1];
  const int bid = blockIdx.x;
  const int pt = bid & 31;         // 32 tiles of 64 p
  const int h  = (bid >> 5) & 1;
  const int b  = bid >> 6;
  const int p0 = pt * 64;
  const int tid = threadIdx.x;

  __shared__ float fl[NC][64];
  for (int i = tid; i < NC*64; i += 256) {
    int c = i >> 6, p = i & 63;
    fl[c][p] = ldf(feat, (b*NC + c)*NP + p0 + p, isb);
  }
  if (h == 0 && tid < 64) {        // canonicalize mask to u8
    unsigned char mv;
    if (mbyte) mv = ((const unsigned char*)mask)[b*NP + p0 + tid] ? 1 : 0;
    else       mv = ((const int*)mask)[b*NP + p0 + tid] ? 1 : 0;
    ((unsigned char*)(ws + WS_MASK8))[b*NP + p0 + tid] = mv;
  }
  __syncthreads();

  const float* g_ew = (const float*)(ws + WS_EW);
  const int e = tid & 63;
  float ew[NC];
#pragma unroll
  for (int c = 0; c < NC; c++) ew[c] = g_ew[(h*NE + e)*NC + c];

  float* eproj = (float*)(ws + WS_EPROJ);
  const int w = tid >> 6;
  const long base = ((long)(b*NH + h)*NP + p0) * NE;
  for (int i = 0; i < 16; i++) {
    int pl = w*16 + i;
    float acc = 0.f;
#pragma unroll
    for (int c = 0; c < NC; c++) acc = fmaf(ew[c], fl[c][pl], acc);
    eproj[base + (long)pl*NE + e] = acc;   // coalesced 256B row
  }
  if (tid < 64) {                  // q and self_score: C=16 dot products
    const float* g_wq    = (const float*)(ws + WS_WQ);
    const float* g_wsc   = (const float*)(ws + WS_WSC);
    const float* g_cself = (const float*)(ws + WS_CSELF);
    float q = 0.f, s = 0.f;
#pragma unroll
    for (int c = 0; c < NC; c++) {
      q = fmaf(g_wq[h*NC+c],  fl[c][tid], q);
      s = fmaf(g_wsc[h*NC+c], fl[c][tid], s);
    }
    ((float*)(ws + WS_QV))[(b*NH + h)*NP + p0 + tid] = q;
    ((float*)(ws + WS_SC))[(b*NH + h)*NP + p0 + tid] = s + g_cself[h];
  }
}

// ---------------- kernel 2: attention + graph max, fused over h --------------
__global__ void __launch_bounds__(256) k_main(const void* nidx_, char* ws, void* out)
{
  const int isb = ((const int*)ws)[0];
  const int* nidx = (const int*)nidx_;
  const unsigned char* m8 = (const unsigned char*)(ws + WS_MASK8);
  const float* qv    = (const float*)(ws + WS_QV);
  const float* sc    = (const float*)(ws + WS_SC);
  const float* eproj = (const float*)(ws + WS_EPROJ);
  const float* g_se  = (const float*)(ws + WS_SE);
  const float* g_cbe = (const float*)(ws + WS_CBE);
  const float* g_cnb = (const float*)(ws + WS_CNB);

  const int bid = blockIdx.x;
  // XCD swizzle: blockIdx%8 selects XCD (round-robin dispatch); pin b-pair per XCD
  const int b  = (bid & 7) * 2 + ((bid >> 3) & 1);
  const int pt = bid >> 4;                 // 0..63
  const int p0 = pt * 32;
  const int tid = threadIdx.x;
  const int w = tid >> 6;                  // wave id: 4 waves x 8 p each
  const int e = tid & 63;                  // lane = E index

  __shared__ float att_t[NE][33];
  __shared__ float gr_t[NE][33];

  for (int j = 0; j < 8; j++) {
    const int pl = w*8 + j;
    const int p  = p0 + pl;
    const int mp = m8[b*NP + p];
    if (!mp) { att_t[e][pl] = 0.f; gr_t[e][pl] = 0.f; continue; }  // output is x0 anyway

    int idxk[NK];
#pragma unroll
    for (int k = 0; k < NK; k++) idxk[k] = nidx[((b*NP) + p)*NK + k];
    unsigned mv = 0;
#pragma unroll
    for (int k = 0; k < NK; k++) if (m8[b*NP + idxk[k]]) mv |= (1u << k);
    const bool anyv = (mv != 0);

    float aacc = -INFINITY, gacc = -INFINITY;
    for (int h = 0; h < NH; h++) {
      const long qb = (long)(b*NH + h)*NP;
      const float qp = qv[qb + p];
      const float ss = sc[qb + p];
      const float cnb = g_cnb[h];
      float lg[NK];
      float mx = -INFINITY;
#pragma unroll
      for (int k = 0; k < NK; k++) {
        float l = ss + qv[qb + idxk[k]] - qp + cnb;
        l = (l >= 0.f) ? l : NSLOPE * l;           // leaky relu
        l = ((mv >> k) & 1) ? l : -INFINITY;       // validity mask
        lg[k] = l;
        mx = fmaxf(mx, l);
      }
      float coef[NK];
      float csum = 0.f;
#pragma unroll
      for (int k = 0; k < NK; k++) {
        float cx = ((mv >> k) & 1) ? __expf(lg[k] - mx) : 0.f;
        coef[k] = cx;
        csum += cx;
      }
      const float inv = anyv ? 1.f / csum : 0.f;

      const long rb = qb * NE;
      float gsum = 0.f, gmx = -INFINITY, gmn = INFINITY;
#pragma unroll
      for (int k = 0; k < NK; k++) {
        float v = eproj[rb + (long)idxk[k]*NE + e];  // coalesced 256B gather
        gsum = fmaf(coef[k], v, gsum);
        if ((mv >> k) & 1) { gmx = fmaxf(gmx, v); gmn = fminf(gmn, v); }
      }
      gsum *= inv;

      const float se   = g_se[h*NE + e];
      const float cb   = g_cbe[h*NE + e];
      const float rawp = eproj[rb + (long)p*NE + e];
      const float cpe  = cb - se * rawp;             // enc[e,k] = se*raw_idx + cpe
      const float csel = anyv ? 1.f : 0.f;
      float att = se * gsum + cpe * csel;            // sum_k coef*enc
      att = fmaxf(att, 0.f);
      float gmsel = (se >= 0.f) ? se * gmx : se * gmn;
      float gr = anyv ? (gmsel + cpe) : 0.f;         // max over valid k, -inf->0
      aacc = fmaxf(aacc, att);
      gacc = fmaxf(gacc, gr);
    }
    att_t[e][pl] = aacc;
    gr_t[e][pl]  = gacc;
  }
  __syncthreads();

  const long obase = (long)b * NE * NP;
  for (int i = tid; i < NE*32; i += 256) {
    const int ee = i >> 5, pp = i & 31;
    const long oi = obase + (long)ee * NP + p0 + pp;
    const float av = att_t[ee][pp], gv = gr_t[ee][pp];
    if (isb) {
      ((__hip_bfloat16*)out)[oi] = __float2bfloat16(av);
      ((__hip_bfloat16*)out)[oi + (long)NB*NE*NP] = __float2bfloat16(gv);
    } else {
      ((float*)out)[oi] = av;
      ((float*)out)[oi + (long)NB*NE*NP] = gv;
    }
  }
}

extern "C" void kernel_launch(void* const* d_in, const int* in_sizes, int n_in,
                              void* d_out, int out_size, void* d_ws, size_t ws_size,
                              hipStream_t stream)
{
  const void* feat      = d_in[0];
  const void* nidx      = d_in[1];
  const void* mask      = d_in[2];
  const void* node_w    = d_in[3];
  const void* node_g    = d_in[4];
  const void* node_b    = d_in[5];
  const void* node_m    = d_in[6];
  const void* node_v    = d_in[7];
  const void* edge_w    = d_in[8];
  const void* edge_bias = d_in[9];
  const void* edge_g    = d_in[10];
  const void* edge_b2   = d_in[11];
  const void* edge_m    = d_in[12];
  const void* edge_v    = d_in[13];
  const void* self_w    = d_in[14];
  const void* self_b    = d_in[15];
  const void* nb_w      = d_in[16];
  const void* nb_b      = d_in[17];
  char* ws = (char*)d_ws;

  hipLaunchKernelGGL(k_pre, dim3(1), dim3(256), 0, stream,
                     feat, mask, node_w, node_g, node_b, node_m, node_v,
                     edge_w, edge_bias, edge_g, edge_b2, edge_m, edge_v,
                     self_w, self_b, nb_w, nb_b, ws);
  hipLaunchKernelGGL(k_proj, dim3(NB*NH*(NP/64)), dim3(256), 0, stream, feat, mask, ws);
  hipLaunchKernelGGL(k_main, dim3(NB*(NP/32)), dim3(256), 0, stream, nidx, ws, d_out);
}

// Round 2
// 140.260 us; speedup vs baseline: 1.1700x; 1.1700x over previous
//
#include <hip/hip_runtime.h>
#include <hip/hip_bf16.h>
#include <math.h>

#define NB 16
#define NC 16
#define NP 2048
#define NK 16
#define NE 64
#define NH 2
#define EPSV 1e-5f
#define NSLOPE 0.2f
#define QINV -1e30f
#define QTHR -1e29f

// workspace byte offsets
#define WS_FLAGS   0                   // 2 ints: [0]=floats-are-bf16, [1]=mask-is-byte
#define WS_EW      256                 // edge_w f32: 2048 floats (8192 B)
#define WS_SE      8448                // s_e: 128 floats
#define WS_CBE     8960                // cbe: 128 floats
#define WS_WQ      9472                // wq: 32 floats
#define WS_WSC     9600                // wsc: 32 floats
#define WS_CNB     9728                // 2 floats
#define WS_CSELF   9744                // 2 floats
#define WS_PINFO   16384               // float4 per (b,p): {q0m,q1m,ss0,ss1} = 512 KiB
#define WS_EPROJ   544768              // [b][p][e][h] f32: 16 MiB (float2 rows)

__device__ __forceinline__ float ldf(const void* p, int i, int isb) {
  return isb ? __bfloat162float(((const __hip_bfloat16*)p)[i]) : ((const float*)p)[i];
}

// ---------------- kernel 0: dtype detection + parameter folding (1 block) ----
__global__ void __launch_bounds__(256) k_pre(
    const void* feat, const void* mask,
    const void* node_w, const void* node_g, const void* node_b,
    const void* node_m, const void* node_v,
    const void* edge_w, const void* edge_bias, const void* edge_g,
    const void* edge_b2, const void* edge_m, const void* edge_v,
    const void* self_w, const void* self_b, const void* nb_w, const void* nb_b,
    char* ws)
{
  __shared__ int cnt_exp, cnt_msk;
  __shared__ int flags[2];
  __shared__ float ewl[NH*NE*NC];      // 8 KiB
  __shared__ float nwl[NH*NE*NC];      // 8 KiB
  __shared__ float w2[NH*NE], wn[NH*NE], contrib[NH*NE], contrib2[NH*NE];
  const int tid = threadIdx.x;
  if (tid == 0) { cnt_exp = 0; cnt_msk = 0; }
  __syncthreads();
  // bf16 N(0,1): exponent field concentrated in [100,135] for ~all samples.
  const unsigned short* u = (const unsigned short*)feat;
  for (int i = tid; i < 512; i += 256) {
    int ex = (u[i] >> 7) & 0xFF;
    if (ex >= 100 && ex <= 135) atomicAdd(&cnt_exp, 1);
  }
  // int32 0/1 mask: non-aligned bytes all zero; bool mask: ~half nonzero.
  const unsigned char* mb = (const unsigned char*)mask;
  for (int i = tid; i < 1024; i += 256) {
    if ((i & 3) && mb[i]) atomicAdd(&cnt_msk, 1);
  }
  __syncthreads();
  if (tid == 0) {
    flags[0] = (cnt_exp >= 460) ? 1 : 0;
    flags[1] = (cnt_msk > 0) ? 1 : 0;
    ((int*)ws)[0] = flags[0];
    ((int*)ws)[1] = flags[1];
  }
  __syncthreads();
  const int isb = flags[0];

  float* g_ew    = (float*)(ws + WS_EW);
  float* g_se    = (float*)(ws + WS_SE);
  float* g_cbe   = (float*)(ws + WS_CBE);
  float* g_wq    = (float*)(ws + WS_WQ);
  float* g_wsc   = (float*)(ws + WS_WSC);
  float* g_cnb   = (float*)(ws + WS_CNB);
  float* g_cself = (float*)(ws + WS_CSELF);

  for (int i = tid; i < NH*NE*NC; i += 256) {
    float v = ldf(edge_w, i, isb);
    ewl[i] = v; g_ew[i] = v;
    nwl[i] = ldf(node_w, i, isb);
  }
  if (tid < NH*NE) {
    const int he = tid;
    float se = ldf(edge_g, he, isb) * rsqrtf(ldf(edge_v, he, isb) + EPSV);
    float cb = se * (ldf(edge_bias, he, isb) - ldf(edge_m, he, isb)) + ldf(edge_b2, he, isb);
    float ns = ldf(node_g, he, isb) * rsqrtf(ldf(node_v, he, isb) + EPSV);
    w2[he] = ldf(nb_w, he, isb) * se;
    wn[he] = ldf(self_w, he, isb) * ns;
    g_se[he] = se;
    g_cbe[he] = cb;
    contrib[he]  = ldf(self_w, he, isb) * (ldf(node_b, he, isb) - ldf(node_m, he, isb) * ns);
    contrib2[he] = ldf(nb_w, he, isb) * cb;
  }
  __syncthreads();
  if (tid < NH*NC) {           // wq[h][c], wsc[h][c] — all operands in LDS now
    const int h = tid >> 4, c = tid & 15;
    float sq = 0.f, sn = 0.f;
#pragma unroll 8
    for (int e = 0; e < NE; e++) {
      sq += w2[h*NE+e] * ewl[(h*NE+e)*NC + c];
      sn += wn[h*NE+e] * nwl[(h*NE+e)*NC + c];
    }
    g_wq[tid]  = sq;
    g_wsc[tid] = sn;
  }
  if (tid < NH) {
    float cs = 0.f, cn = 0.f;
#pragma unroll 8
    for (int e = 0; e < NE; e++) { cs += contrib[tid*NE+e]; cn += contrib2[tid*NE+e]; }
    g_cself[tid] = cs + ldf(self_b, tid, isb);
    g_cnb[tid]   = cn + ldf(nb_b, tid, isb);
  }
}

// ---------------- kernel 1: projection (both heads) + pinfo -----------------
// grid: NB*(NP/64) = 512 blocks; b pinned to XCD pair-wise (matches k_main)
__global__ void __launch_bounds__(256) k_proj(const void* feat, const void* mask, char* ws)
{
  const int isb   = ((const int*)ws)[0];
  const int mbyte = ((const int*)ws)[1];
  const int bid = blockIdx.x;
  const int b  = (bid & 7) * 2 + ((bid >> 3) & 1);   // XCD swizzle
  const int pt = bid >> 4;                           // 0..31
  const int p0 = pt * 64;
  const int tid = threadIdx.x;

  __shared__ float fl[NC][64];
  for (int i = tid; i < NC*64; i += 256) {
    int c = i >> 6, p = i & 63;
    fl[c][p] = ldf(feat, (b*NC + c)*NP + p0 + p, isb);
  }
  __syncthreads();

  const float* g_ew = (const float*)(ws + WS_EW);
  const int c2 = tid & 127;            // col = 2*e + h
  const int e = c2 >> 1, h = c2 & 1;
  const int ph = tid >> 7;             // p parity
  float wv[NC];
#pragma unroll
  for (int c = 0; c < NC; c++) wv[c] = g_ew[(h*NE + e)*NC + c];

  float* eo = (float*)(ws + WS_EPROJ);
  const long base = (long)(b*NP + p0) * 128;
  for (int i = 0; i < 32; i++) {
    const int p = i*2 + ph;
    float acc = 0.f;
#pragma unroll
    for (int c = 0; c < NC; c++) acc = fmaf(wv[c], fl[c][p], acc);  // fl broadcast, no conflict
    eo[base + (long)p*128 + c2] = acc;   // 512B contiguous per p
  }

  if (tid < 64) {                      // q, self_score, mask → pinfo float4
    const float* wq    = (const float*)(ws + WS_WQ);
    const float* wsc   = (const float*)(ws + WS_WSC);
    const float* cself = (const float*)(ws + WS_CSELF);
    float q0=0.f, q1=0.f, s0=0.f, s1=0.f;
#pragma unroll
    for (int c = 0; c < NC; c++) {
      const float f = fl[c][tid];
      q0 = fmaf(wq[c],      f, q0);
      q1 = fmaf(wq[NC+c],   f, q1);
      s0 = fmaf(wsc[c],     f, s0);
      s1 = fmaf(wsc[NC+c],  f, s1);
    }
    const int p = p0 + tid;
    bool mv;
    if (mbyte) mv = ((const unsigned char*)mask)[b*NP + p] != 0;
    else       mv = ((const int*)mask)[b*NP + p] != 0;
    float4 pi;
    pi.x = mv ? q0 : QINV;
    pi.y = mv ? q1 : QINV;
    pi.z = s0 + cself[0];
    pi.w = s1 + cself[1];
    ((float4*)(ws + WS_PINFO))[b*NP + p] = pi;
  }
}

// ---------------- kernel 2: attention + graph max ---------------------------
// grid: NB*(NP/16) = 2048 blocks; 4 waves x 4 p each
__global__ void __launch_bounds__(256, 4) k_main(const int* nidx, char* ws, void* out)
{
  const int isb = ((const int*)ws)[0];
  const float4* pinfo = (const float4*)(ws + WS_PINFO);
  const float2* ep2   = (const float2*)(ws + WS_EPROJ);
  const float* g_se   = (const float*)(ws + WS_SE);
  const float* g_cbe  = (const float*)(ws + WS_CBE);
  const float* g_cnb  = (const float*)(ws + WS_CNB);

  const int bid = blockIdx.x;
  const int b  = (bid & 7) * 2 + ((bid >> 3) & 1);   // XCD swizzle (matches k_proj)
  const int pt = bid >> 4;                           // 0..127
  const int p0 = pt * 16;
  const int tid  = threadIdx.x;
  const int w    = tid >> 6;
  const int lane = tid & 63;
  const int jj = lane >> 4, kk = lane & 15;
  const int pw = p0 + w*4;                           // wave's first p

  __shared__ float4 coef_lds[4][4][NK];              // {c0, c1, idx_bits, -}
  __shared__ float att_t[NE][17];
  __shared__ float gr_t[NE][17];

  const float cnb0 = g_cnb[0], cnb1 = g_cnb[1];

  // ---- phase 1: lanes = (j,k); 64 logits at once, group-16 softmax ----
  const int idx_l = nidx[(b*NP + pw)*NK + lane];     // 256B coalesced
  const float4 P  = pinfo[b*NP + idx_l];             // neighbor: q0m,q1m
  const float4 Pc = pinfo[b*NP + pw + jj];           // central: qp + ss
  const bool valid = (P.x > QTHR);
  const unsigned long long vm  = __ballot(valid);
  const unsigned long long cvm = __ballot(Pc.x > QTHR);
  const unsigned vmj_own = (unsigned)((vm >> (16*jj)) & 0xFFFFull);
  const bool anyv = (vmj_own != 0);

  float c0, c1;
  {
    float l0 = Pc.z + P.x - Pc.x + cnb0;
    l0 = (l0 >= 0.f) ? l0 : NSLOPE * l0;
    float mx = l0;
#pragma unroll
    for (int o = 8; o >= 1; o >>= 1) mx = fmaxf(mx, __shfl_xor(mx, o));
    float ex = __expf(l0 - mx);                      // invalid lanes -> 0
    float sm = ex;
#pragma unroll
    for (int o = 8; o >= 1; o >>= 1) sm += __shfl_xor(sm, o);
    c0 = anyv ? ex / sm : 0.f;
  }
  {
    float l1 = Pc.w + P.y - Pc.y + cnb1;
    l1 = (l1 >= 0.f) ? l1 : NSLOPE * l1;
    float mx = l1;
#pragma unroll
    for (int o = 8; o >= 1; o >>= 1) mx = fmaxf(mx, __shfl_xor(mx, o));
    float ex = __expf(l1 - mx);
    float sm = ex;
#pragma unroll
    for (int o = 8; o >= 1; o >>= 1) sm += __shfl_xor(sm, o);
    c1 = anyv ? ex / sm : 0.f;
  }
  coef_lds[w][jj][kk] = make_float4(c0, c1, __int_as_float(idx_l), 0.f);

  // ---- phase 2: lanes = e; gather eproj rows, weighted sum + masked max ----
  const float se0 = g_se[lane],      se1 = g_se[NE + lane];
  const float cb0 = g_cbe[lane],     cb1 = g_cbe[NE + lane];
  const long rowb = (long)b * NP;

  for (int j = 0; j < 4; j++) {
    const int pj = pw + j;
    const int pl = w*4 + j;
    if (!((cvm >> (16*j)) & 1)) {                    // masked-out central p
      att_t[lane][pl] = 0.f; gr_t[lane][pl] = 0.f; continue;
    }
    const unsigned vmj = (unsigned)((vm >> (16*j)) & 0xFFFFull);
    const bool av = (vmj != 0);
    const float2 rawc = ep2[(rowb + pj)*NE + lane];
    const float cpe0 = cb0 - se0*rawc.x, cpe1 = cb1 - se1*rawc.y;

    float a0 = 0.f, a1 = 0.f;
    float mx0 = -INFINITY, mn0 = INFINITY, mx1 = -INFINITY, mn1 = INFINITY;
#pragma unroll
    for (int k = 0; k < NK; k++) {
      const float4 cf = coef_lds[w][j][k];           // LDS broadcast
      const int ix = __float_as_int(cf.z);
      const float2 v = ep2[(rowb + ix)*NE + lane];   // 512B/wave gather
      a0 = fmaf(cf.x, v.x, a0);
      a1 = fmaf(cf.y, v.y, a1);
      if ((vmj >> k) & 1) {
        mx0 = fmaxf(mx0, v.x); mn0 = fminf(mn0, v.x);
        mx1 = fmaxf(mx1, v.y); mn1 = fminf(mn1, v.y);
      }
    }
    const float csel = av ? 1.f : 0.f;
    const float att0 = fmaxf(fmaf(se0, a0, cpe0*csel), 0.f);
    const float att1 = fmaxf(fmaf(se1, a1, cpe1*csel), 0.f);
    const float g0 = av ? (((se0 >= 0.f) ? se0*mx0 : se0*mn0) + cpe0) : 0.f;
    const float g1 = av ? (((se1 >= 0.f) ? se1*mx1 : se1*mn1) + cpe1) : 0.f;
    att_t[lane][pl] = fmaxf(att0, att1);
    gr_t[lane][pl]  = fmaxf(g0, g1);
  }
  __syncthreads();

  const long obase = (long)b * NE * NP;
  for (int i = tid; i < NE*16; i += 256) {
    const int ee = i >> 4, pp = i & 15;
    const long oi = obase + (long)ee * NP + p0 + pp;
    const float av = att_t[ee][pp], gv = gr_t[ee][pp];
    if (isb) {
      ((__hip_bfloat16*)out)[oi] = __float2bfloat16(av);
      ((__hip_bfloat16*)out)[oi + (long)NB*NE*NP] = __float2bfloat16(gv);
    } else {
      ((float*)out)[oi] = av;
      ((float*)out)[oi + (long)NB*NE*NP] = gv;
    }
  }
}

extern "C" void kernel_launch(void* const* d_in, const int* in_sizes, int n_in,
                              void* d_out, int out_size, void* d_ws, size_t ws_size,
                              hipStream_t stream)
{
  const void* feat      = d_in[0];
  const void* nidx      = d_in[1];
  const void* mask      = d_in[2];
  const void* node_w    = d_in[3];
  const void* node_g    = d_in[4];
  const void* node_b    = d_in[5];
  const void* node_m    = d_in[6];
  const void* node_v    = d_in[7];
  const void* edge_w    = d_in[8];
  const void* edge_bias = d_in[9];
  const void* edge_g    = d_in[10];
  const void* edge_b2   = d_in[11];
  const void* edge_m    = d_in[12];
  const void* edge_v    = d_in[13];
  const void* self_w    = d_in[14];
  const void* self_b    = d_in[15];
  const void* nb_w      = d_in[16];
  const void* nb_b      = d_in[17];
  char* ws = (char*)d_ws;

  hipLaunchKernelGGL(k_pre, dim3(1), dim3(256), 0, stream,
                     feat, mask, node_w, node_g, node_b, node_m, node_v,
                     edge_w, edge_bias, edge_g, edge_b2, edge_m, edge_v,
                     self_w, self_b, nb_w, nb_b, ws);
  hipLaunchKernelGGL(k_proj, dim3(NB*(NP/64)), dim3(256), 0, stream, feat, mask, ws);
  hipLaunchKernelGGL(k_main, dim3(NB*(NP/16)), dim3(256), 0, stream,
                     (const int*)nidx, ws, d_out);
}

// Round 3
// 129.128 us; speedup vs baseline: 1.2709x; 1.0862x over previous
//
#include <hip/hip_runtime.h>
#include <hip/hip_bf16.h>
#include <math.h>

#define NB 16
#define NC 16
#define NP 2048
#define NK 16
#define NE 64
#define NH 2
#define EPSV 1e-5f
#define NSLOPE 0.2f
#define QINV -1e30f
#define QTHR -1e29f

// workspace byte offsets (ws is >= 256 MiB, poisoned 0xAA each iter by harness)
#define WS_PINFO   16384               // float4 per (b,p): {q0m,q1m,ss0,ss1} = 512 KiB
#define WS_EPROJ   544768              // [b][p][e][h] f32 (float2 rows): 16 MiB

__device__ __forceinline__ float ldf(const void* p, int i, int isb) {
  return isb ? __bfloat162float(((const __hip_bfloat16*)p)[i]) : ((const float*)p)[i];
}

// ---------------- kernel 1: projection (both heads) + pinfo -----------------
// grid: NB*(NP/64) = 512 blocks. Parameter fold is recomputed per block
// (deterministic; weight re-reads are L2 broadcasts) -> no k_pre dependency.
__global__ void __launch_bounds__(256) k_proj(
    const void* feat, const void* mask,
    const void* edge_w, const void* node_w,
    const void* edge_g, const void* edge_v, const void* edge_bias,
    const void* edge_m, const void* edge_b2,
    const void* node_g, const void* node_v, const void* node_b, const void* node_m,
    const void* self_w, const void* self_b, const void* nb_w,
    char* ws)
{
  __shared__ int sh_isb, sh_mbyte;
  __shared__ float ewl[128*17];        // padded: bank-conflict-free [he][c]
  __shared__ float nwl[128*17];
  __shared__ float fl[NC][64];
  __shared__ float w2[128], wn[128], ctr[128];
  __shared__ float s_wq[32], s_wsc[32], s_cself[2];

  const int tid = threadIdx.x;
  const int w = tid >> 6, lane = tid & 63;

  // ---- dtype detection (deterministic, identical across blocks) ----
  if (w == 0) {       // bf16 N(0,1): exponent field in [100,135] for ~all samples
    const unsigned short* u = (const unsigned short*)feat;
    int cnt = 0;
#pragma unroll
    for (int i = 0; i < 8; i++) {
      int ex = (u[lane*8 + i] >> 7) & 0xFF;
      cnt += (ex >= 100 && ex <= 135) ? 1 : 0;
    }
#pragma unroll
    for (int o = 32; o >= 1; o >>= 1) cnt += __shfl_xor(cnt, o);
    if (lane == 0) sh_isb = (cnt >= 460) ? 1 : 0;
  }
  if (w == 1) {       // int32 0/1 mask: all non-aligned bytes zero
    const unsigned char* mb = (const unsigned char*)mask;
    int c = 0;
#pragma unroll
    for (int i = 0; i < 16; i++) {
      int ix = lane*16 + i;
      c += ((ix & 3) && mb[ix]) ? 1 : 0;
    }
#pragma unroll
    for (int o = 32; o >= 1; o >>= 1) c += __shfl_xor(c, o);
    if (lane == 0) sh_mbyte = (c > 0) ? 1 : 0;
  }
  __syncthreads();
  const int isb = sh_isb, mbyte = sh_mbyte;

  const int bid = blockIdx.x;
  const int b  = (bid & 7) * 2 + ((bid >> 3) & 1);   // XCD swizzle (matches k_main)
  const int pt = bid >> 4;                           // 0..31
  const int p0 = pt * 64;

  // ---- stage weights + feature tile ----
  for (int i = tid; i < NH*NE*NC; i += 256) {
    const int he = i >> 4, c = i & 15;
    ewl[he*17 + c] = ldf(edge_w, i, isb);
    nwl[he*17 + c] = ldf(node_w, i, isb);
  }
  for (int i = tid; i < NC*64; i += 256) {
    int c = i >> 6, p = i & 63;
    fl[c][p] = ldf(feat, (b*NC + c)*NP + p0 + p, isb);
  }
  if (tid < 128) {
    const int he = tid;
    float se = ldf(edge_g, he, isb) * rsqrtf(ldf(edge_v, he, isb) + EPSV);
    float ns = ldf(node_g, he, isb) * rsqrtf(ldf(node_v, he, isb) + EPSV);
    w2[he]  = ldf(nb_w, he, isb) * se;
    wn[he]  = ldf(self_w, he, isb) * ns;
    ctr[he] = ldf(self_w, he, isb) * (ldf(node_b, he, isb) - ldf(node_m, he, isb) * ns);
  }
  __syncthreads();
  if (tid < NH*NC) {             // wq[h][c], wsc[h][c]
    const int h = tid >> 4, c = tid & 15;
    float sq = 0.f, sn = 0.f;
#pragma unroll 8
    for (int e = 0; e < NE; e++) {
      sq += w2[h*NE+e] * ewl[(h*NE+e)*17 + c];
      sn += wn[h*NE+e] * nwl[(h*NE+e)*17 + c];
    }
    s_wq[tid]  = sq;
    s_wsc[tid] = sn;
  }
  if (tid < NH) {
    float cs = 0.f;
#pragma unroll 8
    for (int e = 0; e < NE; e++) cs += ctr[tid*NE+e];
    s_cself[tid] = cs + ldf(self_b, tid, isb);
  }
  __syncthreads();

  // ---- projection: eproj[b][p][e][h] ----
  const int c2 = tid & 127;            // col = 2*e + h
  const int e = c2 >> 1, h = c2 & 1;
  const int ph = tid >> 7;             // p parity
  float wv[NC];
#pragma unroll
  for (int c = 0; c < NC; c++) wv[c] = ewl[(h*NE + e)*17 + c];

  float* eo = (float*)(ws + WS_EPROJ);
  const long base = (long)(b*NP + p0) * 128;
  for (int i = 0; i < 32; i++) {
    const int p = i*2 + ph;
    float acc = 0.f;
#pragma unroll
    for (int c = 0; c < NC; c++) acc = fmaf(wv[c], fl[c][p], acc);  // fl broadcast
    eo[base + (long)p*128 + c2] = acc;   // 512B contiguous per p
  }

  if (tid < 64) {                      // q, self_score, mask -> pinfo float4
    float q0=0.f, q1=0.f, s0=0.f, s1=0.f;
#pragma unroll
    for (int c = 0; c < NC; c++) {
      const float f = fl[c][tid];
      q0 = fmaf(s_wq[c],      f, q0);
      q1 = fmaf(s_wq[NC+c],   f, q1);
      s0 = fmaf(s_wsc[c],     f, s0);
      s1 = fmaf(s_wsc[NC+c],  f, s1);
    }
    const int p = p0 + tid;
    bool mv;
    if (mbyte) mv = ((const unsigned char*)mask)[b*NP + p] != 0;
    else       mv = ((const int*)mask)[b*NP + p] != 0;
    float4 pi;
    pi.x = mv ? q0 : QINV;
    pi.y = mv ? q1 : QINV;
    pi.z = s0 + s_cself[0];
    pi.w = s1 + s_cself[1];
    ((float4*)(ws + WS_PINFO))[b*NP + p] = pi;
  }
}

// ---------------- kernel 2: attention + graph max ---------------------------
// grid: NB*(NP/32) = 1024 blocks; 4 waves x 8 p each; compacted valid neighbors
__global__ void __launch_bounds__(256, 4) k_main(
    const void* feat, const int* nidx,
    const void* edge_g, const void* edge_v, const void* edge_bias,
    const void* edge_m, const void* edge_b2,
    const void* nb_w, const void* nb_b,
    char* ws, void* out)
{
  __shared__ int sh_isb;
  __shared__ float sh_se[128], sh_cbe[128], sh_cnb[2];
  __shared__ float2 c01[4][8][NK];
  __shared__ int    idxc[4][8][NK];
  __shared__ unsigned char s_cnt[4][8], s_cm[4][8];
  __shared__ float att_t[NE][33];
  __shared__ float gr_t[NE][33];

  const int tid  = threadIdx.x;
  const int w    = tid >> 6;
  const int lane = tid & 63;

  if (w == 0) {                         // dtype detection (same as k_proj)
    const unsigned short* u = (const unsigned short*)feat;
    int cnt = 0;
#pragma unroll
    for (int i = 0; i < 8; i++) {
      int ex = (u[lane*8 + i] >> 7) & 0xFF;
      cnt += (ex >= 100 && ex <= 135) ? 1 : 0;
    }
#pragma unroll
    for (int o = 32; o >= 1; o >>= 1) cnt += __shfl_xor(cnt, o);
    if (lane == 0) sh_isb = (cnt >= 460) ? 1 : 0;
  }
  __syncthreads();
  const int isb = sh_isb;

  if (tid < 128) {                      // fold se/cbe/cnb locally
    const int he = tid, h = tid >> 6;
    float se = ldf(edge_g, he, isb) * rsqrtf(ldf(edge_v, he, isb) + EPSV);
    float cb = se * (ldf(edge_bias, he, isb) - ldf(edge_m, he, isb)) + ldf(edge_b2, he, isb);
    sh_se[he]  = se;
    sh_cbe[he] = cb;
    float t = ldf(nb_w, he, isb) * cb;
#pragma unroll
    for (int o = 32; o >= 1; o >>= 1) t += __shfl_xor(t, o);
    if ((tid & 63) == 0) sh_cnb[h] = t + ldf(nb_b, h, isb);
  }
  __syncthreads();

  const float4* pinfo = (const float4*)(ws + WS_PINFO);
  const float2* ep2   = (const float2*)(ws + WS_EPROJ);

  const int bid = blockIdx.x;
  const int b  = (bid & 7) * 2 + ((bid >> 3) & 1);   // XCD swizzle (matches k_proj)
  const int pt = bid >> 4;                           // 0..63
  const int p0 = pt * 32;
  const int jj = lane >> 4, kk = lane & 15;
  const float cnb0 = sh_cnb[0], cnb1 = sh_cnb[1];

  // ---- phase 1: lanes = (j,k); softmax + compaction of valid neighbors ----
  for (int jr = 0; jr < 2; jr++) {
    const int pw4 = p0 + w*8 + jr*4;
    const int idx_l = nidx[(b*NP + pw4)*NK + lane];  // 256B coalesced
    const float4 P  = pinfo[b*NP + idx_l];
    const float4 Pc = pinfo[b*NP + pw4 + jj];
    const bool valid = (P.x > QTHR);
    const unsigned long long vm = __ballot(valid);
    const unsigned vmj = (unsigned)((vm >> (16*jj)) & 0xFFFFull);
    const bool anyv = (vmj != 0);

    float c0, c1;
    {
      float l0 = Pc.z + P.x - Pc.x + cnb0;
      l0 = (l0 >= 0.f) ? l0 : NSLOPE * l0;
      float mx = l0;
#pragma unroll
      for (int o = 8; o >= 1; o >>= 1) mx = fmaxf(mx, __shfl_xor(mx, o));
      float ex = __expf(l0 - mx);
      float sm = ex;
#pragma unroll
      for (int o = 8; o >= 1; o >>= 1) sm += __shfl_xor(sm, o);
      c0 = anyv ? ex / sm : 0.f;
    }
    {
      float l1 = Pc.w + P.y - Pc.y + cnb1;
      l1 = (l1 >= 0.f) ? l1 : NSLOPE * l1;
      float mx = l1;
#pragma unroll
      for (int o = 8; o >= 1; o >>= 1) mx = fmaxf(mx, __shfl_xor(mx, o));
      float ex = __expf(l1 - mx);
      float sm = ex;
#pragma unroll
      for (int o = 8; o >= 1; o >>= 1) sm += __shfl_xor(sm, o);
      c1 = anyv ? ex / sm : 0.f;
    }
    const int jx = jr*4 + jj;
    const int pos = __popc(vmj & ((1u << kk) - 1));
    if (valid) {
      c01[w][jx][pos]  = make_float2(c0, c1);
      idxc[w][jx][pos] = idx_l;
    }
    if (kk == 0) {
      s_cnt[w][jx] = (unsigned char)__popc(vmj);
      s_cm[w][jx]  = (Pc.x > QTHR) ? 1 : 0;
    }
  }
  // same-wave LDS produce->consume: program order, no barrier needed

  // ---- phase 2: lanes = e; gather compacted rows, weighted sum + max ----
  const float se0 = sh_se[lane],  se1 = sh_se[NE + lane];
  const float cb0 = sh_cbe[lane], cb1 = sh_cbe[NE + lane];
  const long rowb = (long)b * NP;

  for (int j = 0; j < 8; j++) {
    const int pj = p0 + w*8 + j;
    const int pl = w*8 + j;
    if (!s_cm[w][j]) { att_t[lane][pl] = 0.f; gr_t[lane][pl] = 0.f; continue; }
    const int cnt = s_cnt[w][j];
    const float2 rawc = ep2[(rowb + pj)*NE + lane];
    const float cpe0 = cb0 - se0*rawc.x, cpe1 = cb1 - se1*rawc.y;

    float a0 = 0.f, a1 = 0.f;
    float mx0 = -INFINITY, mn0 = INFINITY, mx1 = -INFINITY, mn1 = INFINITY;
#pragma unroll 4
    for (int k = 0; k < cnt; k++) {
      const float2 cf = c01[w][j][k];              // LDS broadcast
      const int ix = idxc[w][j][k];
      const float2 v = ep2[(rowb + ix)*NE + lane]; // 512B/wave gather, all valid
      a0 = fmaf(cf.x, v.x, a0);
      a1 = fmaf(cf.y, v.y, a1);
      mx0 = fmaxf(mx0, v.x); mn0 = fminf(mn0, v.x);
      mx1 = fmaxf(mx1, v.y); mn1 = fminf(mn1, v.y);
    }
    const bool av = (cnt > 0);
    const float csel = av ? 1.f : 0.f;
    const float att0 = fmaxf(fmaf(se0, a0, cpe0*csel), 0.f);
    const float att1 = fmaxf(fmaf(se1, a1, cpe1*csel), 0.f);
    const float g0 = av ? (((se0 >= 0.f) ? se0*mx0 : se0*mn0) + cpe0) : 0.f;
    const float g1 = av ? (((se1 >= 0.f) ? se1*mx1 : se1*mn1) + cpe1) : 0.f;
    att_t[lane][pl] = fmaxf(att0, att1);
    gr_t[lane][pl]  = fmaxf(g0, g1);
  }
  __syncthreads();

  const long obase = (long)b * NE * NP;
  for (int i = tid; i < NE*32; i += 256) {
    const int ee = i >> 5, pp = i & 31;
    const long oi = obase + (long)ee * NP + p0 + pp;
    const float av = att_t[ee][pp], gv = gr_t[ee][pp];
    if (isb) {
      ((__hip_bfloat16*)out)[oi] = __float2bfloat16(av);
      ((__hip_bfloat16*)out)[oi + (long)NB*NE*NP] = __float2bfloat16(gv);
    } else {
      ((float*)out)[oi] = av;
      ((float*)out)[oi + (long)NB*NE*NP] = gv;
    }
  }
}

extern "C" void kernel_launch(void* const* d_in, const int* in_sizes, int n_in,
                              void* d_out, int out_size, void* d_ws, size_t ws_size,
                              hipStream_t stream)
{
  const void* feat      = d_in[0];
  const void* nidx      = d_in[1];
  const void* mask      = d_in[2];
  const void* node_w    = d_in[3];
  const void* node_g    = d_in[4];
  const void* node_b    = d_in[5];
  const void* node_m    = d_in[6];
  const void* node_v    = d_in[7];
  const void* edge_w    = d_in[8];
  const void* edge_bias = d_in[9];
  const void* edge_g    = d_in[10];
  const void* edge_b2   = d_in[11];
  const void* edge_m    = d_in[12];
  const void* edge_v    = d_in[13];
  const void* self_w    = d_in[14];
  const void* self_b    = d_in[15];
  const void* nb_w      = d_in[16];
  const void* nb_b      = d_in[17];
  char* ws = (char*)d_ws;

  hipLaunchKernelGGL(k_proj, dim3(NB*(NP/64)), dim3(256), 0, stream,
                     feat, mask, edge_w, node_w,
                     edge_g, edge_v, edge_bias, edge_m, edge_b2,
                     node_g, node_v, node_b, node_m,
                     self_w, self_b, nb_w, ws);
  hipLaunchKernelGGL(k_main, dim3(NB*(NP/32)), dim3(256), 0, stream,
                     feat, (const int*)nidx,
                     edge_g, edge_v, edge_bias, edge_m, edge_b2,
                     nb_w, nb_b, ws, d_out);
}